// Round 1
// baseline (4331.366 us; speedup 1.0000x reference)
//
#include <hip/hip_runtime.h>
#include <cstddef>
#include <cstdint>

// Problem constants (match reference)
#define N_SRC1 1210000
#define N_DST1 110000
#define N_SRC2 110000
#define N_DST2 10000
#define E1 1100000
#define E2 100000
#define IN_DIM 128
#define HID_DIM 256
#define OUT_DIM 128

// ---------------- degree accumulation ----------------
__global__ __launch_bounds__(256) void deg_kernel(const int* __restrict__ src,
                                                  const int* __restrict__ dst,
                                                  float* __restrict__ outdeg,
                                                  float* __restrict__ indeg, int E) {
    int i = blockIdx.x * 256 + threadIdx.x;
    if (i < E) {
        unsafeAtomicAdd(&outdeg[src[i]], 1.0f);
        unsafeAtomicAdd(&indeg[dst[i]], 1.0f);
    }
}

// deg -> rsqrt(max(deg,1)) in place
__global__ __launch_bounds__(256) void rsqrt_kernel(float* __restrict__ p, int n) {
    int i = blockIdx.x * 256 + threadIdx.x;
    if (i < n) p[i] = rsqrtf(fmaxf(p[i], 1.0f));
}

// ---------------- layer-1 edge scatter ----------------
// 32 threads per edge, float4 per thread (128 floats). 8 edges / 256-thread block.
__global__ __launch_bounds__(256) void scatter1_kernel(const float* __restrict__ feat,
                                                       const int* __restrict__ src,
                                                       const int* __restrict__ dst,
                                                       const float* __restrict__ rs_out,
                                                       float* __restrict__ agg, int E) {
    int e = blockIdx.x * 8 + (threadIdx.x >> 5);
    if (e >= E) return;
    int lane = threadIdx.x & 31;
    int s = src[e], d = dst[e];
    float sc = rs_out[s];
    float4 v = ((const float4*)(feat + (size_t)s * IN_DIM))[lane];
    float* p = agg + (size_t)d * IN_DIM + lane * 4;
    unsafeAtomicAdd(p + 0, v.x * sc);
    unsafeAtomicAdd(p + 1, v.y * sc);
    unsafeAtomicAdd(p + 2, v.z * sc);
    unsafeAtomicAdd(p + 3, v.w * sc);
}

// ---------------- layer-2 edge scatter ----------------
// 64 threads per edge, float4 per thread (256 floats). 4 edges / block.
__global__ __launch_bounds__(256) void scatter2_kernel(const float* __restrict__ h1,
                                                       const int* __restrict__ src,
                                                       const int* __restrict__ dst,
                                                       const float* __restrict__ rs_out,
                                                       float* __restrict__ agg, int E) {
    int e = blockIdx.x * 4 + (threadIdx.x >> 6);
    if (e >= E) return;
    int lane = threadIdx.x & 63;
    int s = src[e], d = dst[e];
    float sc = rs_out[s];
    float4 v = ((const float4*)(h1 + (size_t)s * HID_DIM))[lane];
    float* p = agg + (size_t)d * HID_DIM + lane * 4;
    unsafeAtomicAdd(p + 0, v.x * sc);
    unsafeAtomicAdd(p + 1, v.y * sc);
    unsafeAtomicAdd(p + 2, v.z * sc);
    unsafeAtomicAdd(p + 3, v.w * sc);
}

// ---------------- GEMM1 + bias + sigmoid gate ----------------
// C(110000x256) = (agg1 * rsqrt(indeg1)) @ W1 + b1 ; alpha=sigmoid(C@attn1); h1=C*alpha
// Block: 256 thr, 64 rows x 256 cols. Thread: 16 rows x 4 cols.
// Within a wave: all 64 lanes share rbase, cols cover 0..255 -> wave shuffle = full row dot.
__global__ __launch_bounds__(256) void gemm1_gate(const float* __restrict__ agg,
                                                  const float* __restrict__ rs_in,
                                                  const float* __restrict__ W,
                                                  const float* __restrict__ bias,
                                                  const float* __restrict__ attn,
                                                  float* __restrict__ h1, int M) {
    __shared__ float As[64][IN_DIM + 4];
    __shared__ float Bs[32][HID_DIM];
    const int t = threadIdx.x;
    const int row0 = blockIdx.x * 64;
    const int col = t & 63;          // *4 -> cols
    const int rbase = (t >> 6) * 16; // wave-uniform

    // Load A tile (64x128) with dst-side norm
    #pragma unroll
    for (int i = 0; i < 8; ++i) {
        int idx = t + i * 256;          // 0..2047 float4 slots
        int r = idx >> 5, c4 = idx & 31;
        int row = row0 + r;
        float4 v = make_float4(0.f, 0.f, 0.f, 0.f);
        if (row < M) {
            v = ((const float4*)(agg + (size_t)row * IN_DIM))[c4];
            float s = rs_in[row];
            v.x *= s; v.y *= s; v.z *= s; v.w *= s;
        }
        *(float4*)&As[r][c4 * 4] = v;
    }

    float4 acc[16];
    #pragma unroll
    for (int rr = 0; rr < 16; ++rr) acc[rr] = make_float4(0.f, 0.f, 0.f, 0.f);

    for (int kc = 0; kc < 4; ++kc) {   // K chunks of 32
        __syncthreads();
        #pragma unroll
        for (int i = 0; i < 8; ++i) {
            int idx = t + i * 256;      // 0..2047 float4 slots (32x64)
            int kk = idx >> 6, c4 = idx & 63;
            *(float4*)&Bs[kk][c4 * 4] = ((const float4*)(W + (size_t)(kc * 32 + kk) * HID_DIM))[c4];
        }
        __syncthreads();
        #pragma unroll
        for (int k4 = 0; k4 < 8; ++k4) {
            int kk = k4 * 4;
            float4 b0 = *(float4*)&Bs[kk + 0][col * 4];
            float4 b1v = *(float4*)&Bs[kk + 1][col * 4];
            float4 b2v = *(float4*)&Bs[kk + 2][col * 4];
            float4 b3v = *(float4*)&Bs[kk + 3][col * 4];
            int ka = kc * 32 + kk;
            #pragma unroll
            for (int rr = 0; rr < 16; ++rr) {
                float4 a = *(const float4*)&As[rbase + rr][ka];
                acc[rr].x += a.x * b0.x + a.y * b1v.x + a.z * b2v.x + a.w * b3v.x;
                acc[rr].y += a.x * b0.y + a.y * b1v.y + a.z * b2v.y + a.w * b3v.y;
                acc[rr].z += a.x * b0.z + a.y * b1v.z + a.z * b2v.z + a.w * b3v.z;
                acc[rr].w += a.x * b0.w + a.y * b1v.w + a.z * b2v.w + a.w * b3v.w;
            }
        }
    }

    // Epilogue: bias, gate, store
    float4 bb = *(const float4*)&bias[col * 4];
    float4 at = *(const float4*)&attn[col * 4];
    #pragma unroll
    for (int rr = 0; rr < 16; ++rr) {
        int row = row0 + rbase + rr;
        float4 v = acc[rr];
        v.x += bb.x; v.y += bb.y; v.z += bb.z; v.w += bb.w;
        float p = v.x * at.x + v.y * at.y + v.z * at.z + v.w * at.w;
        p += __shfl_down(p, 32);
        p += __shfl_down(p, 16);
        p += __shfl_down(p, 8);
        p += __shfl_down(p, 4);
        p += __shfl_down(p, 2);
        p += __shfl_down(p, 1);
        p = __shfl(p, 0);
        float alpha = 1.f / (1.f + expf(-p));
        v.x *= alpha; v.y *= alpha; v.z *= alpha; v.w *= alpha;
        if (row < M) *(float4*)&h1[(size_t)row * HID_DIM + col * 4] = v;
    }
}

// ---------------- GEMM2 + bias + sigmoid gate -> outputs ----------------
// C(10000x128) = (agg2 * rsqrt(indeg2)) @ W2 + b2 ; alpha=sigmoid(C@attn2)
// out_h = C*alpha (10000x128), out_alpha (10000)
// Block: 256 thr, 32 rows x 128 cols. Thread: 8 rows x 2 cols.
__global__ __launch_bounds__(256) void gemm2_gate(const float* __restrict__ agg,
                                                  const float* __restrict__ rs_in,
                                                  const float* __restrict__ W,
                                                  const float* __restrict__ bias,
                                                  const float* __restrict__ attn,
                                                  float* __restrict__ out_h,
                                                  float* __restrict__ out_alpha, int M) {
    __shared__ float As[32][HID_DIM + 4];
    __shared__ float Bs[32][OUT_DIM];
    const int t = threadIdx.x;
    const int row0 = blockIdx.x * 32;
    const int col = t & 63;         // *2 -> cols
    const int rbase = (t >> 6) * 8; // wave-uniform

    #pragma unroll
    for (int i = 0; i < 8; ++i) {
        int idx = t + i * 256;       // 0..2047 float4 slots (32x64)
        int r = idx >> 6, c4 = idx & 63;
        int row = row0 + r;
        float4 v = make_float4(0.f, 0.f, 0.f, 0.f);
        if (row < M) {
            v = ((const float4*)(agg + (size_t)row * HID_DIM))[c4];
            float s = rs_in[row];
            v.x *= s; v.y *= s; v.z *= s; v.w *= s;
        }
        *(float4*)&As[r][c4 * 4] = v;
    }

    float2 acc[8];
    #pragma unroll
    for (int rr = 0; rr < 8; ++rr) acc[rr] = make_float2(0.f, 0.f);

    for (int kc = 0; kc < 8; ++kc) {   // K=256, chunks of 32
        __syncthreads();
        #pragma unroll
        for (int i = 0; i < 4; ++i) {
            int idx = t + i * 256;      // 0..1023 float4 slots (32x32)
            int kk = idx >> 5, c4 = idx & 31;
            *(float4*)&Bs[kk][c4 * 4] = ((const float4*)(W + (size_t)(kc * 32 + kk) * OUT_DIM))[c4];
        }
        __syncthreads();
        #pragma unroll
        for (int k4 = 0; k4 < 8; ++k4) {
            int kk = k4 * 4;
            float2 b0 = *(float2*)&Bs[kk + 0][col * 2];
            float2 b1v = *(float2*)&Bs[kk + 1][col * 2];
            float2 b2v = *(float2*)&Bs[kk + 2][col * 2];
            float2 b3v = *(float2*)&Bs[kk + 3][col * 2];
            int ka = kc * 32 + kk;
            #pragma unroll
            for (int rr = 0; rr < 8; ++rr) {
                float4 a = *(const float4*)&As[rbase + rr][ka];
                acc[rr].x += a.x * b0.x + a.y * b1v.x + a.z * b2v.x + a.w * b3v.x;
                acc[rr].y += a.x * b0.y + a.y * b1v.y + a.z * b2v.y + a.w * b3v.y;
            }
        }
    }

    float2 bb = *(const float2*)&bias[col * 2];
    float2 at = *(const float2*)&attn[col * 2];
    #pragma unroll
    for (int rr = 0; rr < 8; ++rr) {
        int row = row0 + rbase + rr;
        float2 v = acc[rr];
        v.x += bb.x; v.y += bb.y;
        float p = v.x * at.x + v.y * at.y;
        p += __shfl_down(p, 32);
        p += __shfl_down(p, 16);
        p += __shfl_down(p, 8);
        p += __shfl_down(p, 4);
        p += __shfl_down(p, 2);
        p += __shfl_down(p, 1);
        p = __shfl(p, 0);
        float alpha = 1.f / (1.f + expf(-p));
        v.x *= alpha; v.y *= alpha;
        if (row < M) {
            *(float2*)&out_h[(size_t)row * OUT_DIM + col * 2] = v;
            if (col == 0) out_alpha[row] = alpha;
        }
    }
}

extern "C" void kernel_launch(void* const* d_in, const int* in_sizes, int n_in,
                              void* d_out, int out_size, void* d_ws, size_t ws_size,
                              hipStream_t stream) {
    const float* feat  = (const float*)d_in[0];
    const float* W1    = (const float*)d_in[1];
    const float* b1    = (const float*)d_in[2];
    const float* attn1 = (const float*)d_in[3];
    const float* W2    = (const float*)d_in[4];
    const float* b2    = (const float*)d_in[5];
    const float* attn2 = (const float*)d_in[6];
    const int* src1 = (const int*)d_in[7];
    const int* dst1 = (const int*)d_in[8];
    const int* src2 = (const int*)d_in[9];
    const int* dst2 = (const int*)d_in[10];
    float* out = (float*)d_out;

    float* ws = (float*)d_ws;
    float* outdeg1 = ws;                         // 1,210,000
    float* indeg1  = outdeg1 + N_SRC1;           // 110,000
    float* outdeg2 = indeg1 + N_DST1;            // 110,000
    float* indeg2  = outdeg2 + N_SRC2;           // 10,000
    float* agg1    = indeg2 + N_DST2;            // 110,000*128
    float* agg2    = agg1 + (size_t)N_DST1 * IN_DIM;   // 10,000*256
    float* h1      = agg2 + (size_t)N_DST2 * HID_DIM;  // 110,000*256

    const int n_deg = N_SRC1 + N_DST1 + N_SRC2 + N_DST2;            // 1,440,000
    const size_t zero_floats = (size_t)n_deg + (size_t)N_DST1 * IN_DIM + (size_t)N_DST2 * HID_DIM;
    hipMemsetAsync(d_ws, 0, zero_floats * sizeof(float), stream);

    deg_kernel<<<(E1 + 255) / 256, 256, 0, stream>>>(src1, dst1, outdeg1, indeg1, E1);
    deg_kernel<<<(E2 + 255) / 256, 256, 0, stream>>>(src2, dst2, outdeg2, indeg2, E2);
    rsqrt_kernel<<<(n_deg + 255) / 256, 256, 0, stream>>>(ws, n_deg);

    scatter1_kernel<<<(E1 + 7) / 8, 256, 0, stream>>>(feat, src1, dst1, outdeg1, agg1, E1);
    gemm1_gate<<<(N_DST1 + 63) / 64, 256, 0, stream>>>(agg1, indeg1, W1, b1, attn1, h1, N_DST1);
    scatter2_kernel<<<(E2 + 3) / 4, 256, 0, stream>>>(h1, src2, dst2, outdeg2, agg2, E2);
    gemm2_gate<<<(N_DST2 + 31) / 32, 256, 0, stream>>>(agg2, indeg2, W2, b2, attn2,
                                                       out, out + (size_t)N_DST2 * OUT_DIM, N_DST2);
}

// Round 2
// 2695.717 us; speedup vs baseline: 1.6068x; 1.6068x over previous
//
#include <hip/hip_runtime.h>
#include <cstddef>
#include <cstdint>

// Problem constants (match reference)
#define N_SRC1 1210000
#define N_DST1 110000
#define N_SRC2 110000
#define N_DST2 10000
#define E1 1100000
#define E2 100000
#define IN_DIM 128
#define HID_DIM 256
#define OUT_DIM 128

// ---------------- degree + dst-count accumulation ----------------
__global__ __launch_bounds__(256) void count_kernel(const int* __restrict__ src,
                                                    const int* __restrict__ dst,
                                                    float* __restrict__ outdeg,
                                                    int* __restrict__ cnt, int E) {
    int i = blockIdx.x * 256 + threadIdx.x;
    if (i < E) {
        unsafeAtomicAdd(&outdeg[src[i]], 1.0f);
        atomicAdd(&cnt[dst[i]], 1);
    }
}

// deg -> rsqrt(max(deg,1)) in place
__global__ __launch_bounds__(256) void rsqrt_kernel(float* __restrict__ p, int n) {
    int i = blockIdx.x * 256 + threadIdx.x;
    if (i < n) p[i] = rsqrtf(fmaxf(p[i], 1.0f));
}

// ---------------- single-block exclusive scan (counts -> offsets + cursor) ----------------
__global__ __launch_bounds__(1024) void scan_kernel(const int* __restrict__ cnt,
                                                    int* __restrict__ offs,
                                                    int* __restrict__ cursor, int n) {
    __shared__ int smem[1024];
    __shared__ int running;
    if (threadIdx.x == 0) running = 0;
    __syncthreads();
    for (int base = 0; base < n; base += 1024) {
        int i = base + threadIdx.x;
        int v = (i < n) ? cnt[i] : 0;
        smem[threadIdx.x] = v;
        __syncthreads();
        #pragma unroll
        for (int off = 1; off < 1024; off <<= 1) {
            int t = (threadIdx.x >= off) ? smem[threadIdx.x - off] : 0;
            __syncthreads();
            smem[threadIdx.x] += t;
            __syncthreads();
        }
        int excl = smem[threadIdx.x] - v + running;
        if (i < n) { offs[i] = excl; cursor[i] = excl; }
        __syncthreads();
        if (threadIdx.x == 0) running += smem[1023];
        __syncthreads();
    }
    if (threadIdx.x == 0) offs[n] = running;
}

// ---------------- bucket fill: edge src ids grouped by dst ----------------
__global__ __launch_bounds__(256) void fill_kernel(const int* __restrict__ src,
                                                   const int* __restrict__ dst,
                                                   int* __restrict__ cursor,
                                                   int* __restrict__ elist, int E) {
    int i = blockIdx.x * 256 + threadIdx.x;
    if (i < E) {
        int pos = atomicAdd(&cursor[dst[i]], 1);
        elist[pos] = src[i];
    }
}

// ---------------- layer-1 gather: one wave (64 lanes x float2) per dst row ----------------
// agg[d] = rsqrt(indeg[d]) * sum_{s in N(d)} feat[s] * rsqrt(outdeg[s])
__global__ __launch_bounds__(256) void gather1_kernel(const float* __restrict__ feat,
                                                      const int* __restrict__ elist,
                                                      const int* __restrict__ offs,
                                                      const float* __restrict__ rs_out,
                                                      float* __restrict__ agg, int n_dst) {
    int d = blockIdx.x * 4 + (threadIdx.x >> 6);
    if (d >= n_dst) return;
    int lane = threadIdx.x & 63;
    int beg = offs[d], end = offs[d + 1];
    float2 acc = make_float2(0.f, 0.f);
    for (int j = beg; j < end; ++j) {
        int s = elist[j];
        float sc = rs_out[s];
        float2 v = ((const float2*)(feat + (size_t)s * IN_DIM))[lane];
        acc.x += v.x * sc;
        acc.y += v.y * sc;
    }
    float rin = rsqrtf(fmaxf((float)(end - beg), 1.f));
    acc.x *= rin; acc.y *= rin;
    ((float2*)(agg + (size_t)d * IN_DIM))[lane] = acc;
}

// ---------------- layer-2 gather: one wave (64 lanes x float4) per dst row ----------------
__global__ __launch_bounds__(256) void gather2_kernel(const float* __restrict__ h1,
                                                      const int* __restrict__ elist,
                                                      const int* __restrict__ offs,
                                                      const float* __restrict__ rs_out,
                                                      float* __restrict__ agg, int n_dst) {
    int d = blockIdx.x * 4 + (threadIdx.x >> 6);
    if (d >= n_dst) return;
    int lane = threadIdx.x & 63;
    int beg = offs[d], end = offs[d + 1];
    float4 acc = make_float4(0.f, 0.f, 0.f, 0.f);
    for (int j = beg; j < end; ++j) {
        int s = elist[j];
        float sc = rs_out[s];
        float4 v = ((const float4*)(h1 + (size_t)s * HID_DIM))[lane];
        acc.x += v.x * sc;
        acc.y += v.y * sc;
        acc.z += v.z * sc;
        acc.w += v.w * sc;
    }
    float rin = rsqrtf(fmaxf((float)(end - beg), 1.f));
    acc.x *= rin; acc.y *= rin; acc.z *= rin; acc.w *= rin;
    ((float4*)(agg + (size_t)d * HID_DIM))[lane] = acc;
}

// ---------------- GEMM1 + bias + sigmoid gate ----------------
// C(110000x256) = agg1 @ W1 + b1 ; alpha=sigmoid(C@attn1); h1=C*alpha
// Block: 256 thr, 64 rows x 256 cols. Thread: 16 rows x 4 cols.
__global__ __launch_bounds__(256) void gemm1_gate(const float* __restrict__ agg,
                                                  const float* __restrict__ W,
                                                  const float* __restrict__ bias,
                                                  const float* __restrict__ attn,
                                                  float* __restrict__ h1, int M) {
    __shared__ float As[64][IN_DIM + 4];
    __shared__ float Bs[32][HID_DIM];
    const int t = threadIdx.x;
    const int row0 = blockIdx.x * 64;
    const int col = t & 63;          // *4 -> cols
    const int rbase = (t >> 6) * 16; // wave-uniform

    #pragma unroll
    for (int i = 0; i < 8; ++i) {
        int idx = t + i * 256;          // 0..2047 float4 slots
        int r = idx >> 5, c4 = idx & 31;
        int row = row0 + r;
        float4 v = make_float4(0.f, 0.f, 0.f, 0.f);
        if (row < M) v = ((const float4*)(agg + (size_t)row * IN_DIM))[c4];
        *(float4*)&As[r][c4 * 4] = v;
    }

    float4 acc[16];
    #pragma unroll
    for (int rr = 0; rr < 16; ++rr) acc[rr] = make_float4(0.f, 0.f, 0.f, 0.f);

    for (int kc = 0; kc < 4; ++kc) {   // K chunks of 32
        __syncthreads();
        #pragma unroll
        for (int i = 0; i < 8; ++i) {
            int idx = t + i * 256;      // 0..2047 float4 slots (32x64)
            int kk = idx >> 6, c4 = idx & 63;
            *(float4*)&Bs[kk][c4 * 4] = ((const float4*)(W + (size_t)(kc * 32 + kk) * HID_DIM))[c4];
        }
        __syncthreads();
        #pragma unroll
        for (int k4 = 0; k4 < 8; ++k4) {
            int kk = k4 * 4;
            float4 b0 = *(float4*)&Bs[kk + 0][col * 4];
            float4 b1v = *(float4*)&Bs[kk + 1][col * 4];
            float4 b2v = *(float4*)&Bs[kk + 2][col * 4];
            float4 b3v = *(float4*)&Bs[kk + 3][col * 4];
            int ka = kc * 32 + kk;
            #pragma unroll
            for (int rr = 0; rr < 16; ++rr) {
                float4 a = *(const float4*)&As[rbase + rr][ka];
                acc[rr].x += a.x * b0.x + a.y * b1v.x + a.z * b2v.x + a.w * b3v.x;
                acc[rr].y += a.x * b0.y + a.y * b1v.y + a.z * b2v.y + a.w * b3v.y;
                acc[rr].z += a.x * b0.z + a.y * b1v.z + a.z * b2v.z + a.w * b3v.z;
                acc[rr].w += a.x * b0.w + a.y * b1v.w + a.z * b2v.w + a.w * b3v.w;
            }
        }
    }

    float4 bb = *(const float4*)&bias[col * 4];
    float4 at = *(const float4*)&attn[col * 4];
    #pragma unroll
    for (int rr = 0; rr < 16; ++rr) {
        int row = row0 + rbase + rr;
        float4 v = acc[rr];
        v.x += bb.x; v.y += bb.y; v.z += bb.z; v.w += bb.w;
        float p = v.x * at.x + v.y * at.y + v.z * at.z + v.w * at.w;
        p += __shfl_down(p, 32);
        p += __shfl_down(p, 16);
        p += __shfl_down(p, 8);
        p += __shfl_down(p, 4);
        p += __shfl_down(p, 2);
        p += __shfl_down(p, 1);
        p = __shfl(p, 0);
        float alpha = 1.f / (1.f + expf(-p));
        v.x *= alpha; v.y *= alpha; v.z *= alpha; v.w *= alpha;
        if (row < M) *(float4*)&h1[(size_t)row * HID_DIM + col * 4] = v;
    }
}

// ---------------- GEMM2 + bias + sigmoid gate -> outputs ----------------
__global__ __launch_bounds__(256) void gemm2_gate(const float* __restrict__ agg,
                                                  const float* __restrict__ W,
                                                  const float* __restrict__ bias,
                                                  const float* __restrict__ attn,
                                                  float* __restrict__ out_h,
                                                  float* __restrict__ out_alpha, int M) {
    __shared__ float As[32][HID_DIM + 4];
    __shared__ float Bs[32][OUT_DIM];
    const int t = threadIdx.x;
    const int row0 = blockIdx.x * 32;
    const int col = t & 63;         // *2 -> cols
    const int rbase = (t >> 6) * 8; // wave-uniform

    #pragma unroll
    for (int i = 0; i < 8; ++i) {
        int idx = t + i * 256;       // 0..2047 float4 slots (32x64)
        int r = idx >> 6, c4 = idx & 63;
        int row = row0 + r;
        float4 v = make_float4(0.f, 0.f, 0.f, 0.f);
        if (row < M) v = ((const float4*)(agg + (size_t)row * HID_DIM))[c4];
        *(float4*)&As[r][c4 * 4] = v;
    }

    float2 acc[8];
    #pragma unroll
    for (int rr = 0; rr < 8; ++rr) acc[rr] = make_float2(0.f, 0.f);

    for (int kc = 0; kc < 8; ++kc) {   // K=256, chunks of 32
        __syncthreads();
        #pragma unroll
        for (int i = 0; i < 4; ++i) {
            int idx = t + i * 256;      // 0..1023 float4 slots (32x32)
            int kk = idx >> 5, c4 = idx & 31;
            *(float4*)&Bs[kk][c4 * 4] = ((const float4*)(W + (size_t)(kc * 32 + kk) * OUT_DIM))[c4];
        }
        __syncthreads();
        #pragma unroll
        for (int k4 = 0; k4 < 8; ++k4) {
            int kk = k4 * 4;
            float2 b0 = *(float2*)&Bs[kk + 0][col * 2];
            float2 b1v = *(float2*)&Bs[kk + 1][col * 2];
            float2 b2v = *(float2*)&Bs[kk + 2][col * 2];
            float2 b3v = *(float2*)&Bs[kk + 3][col * 2];
            int ka = kc * 32 + kk;
            #pragma unroll
            for (int rr = 0; rr < 8; ++rr) {
                float4 a = *(const float4*)&As[rbase + rr][ka];
                acc[rr].x += a.x * b0.x + a.y * b1v.x + a.z * b2v.x + a.w * b3v.x;
                acc[rr].y += a.x * b0.y + a.y * b1v.y + a.z * b2v.y + a.w * b3v.y;
            }
        }
    }

    float2 bb = *(const float2*)&bias[col * 2];
    float2 at = *(const float2*)&attn[col * 2];
    #pragma unroll
    for (int rr = 0; rr < 8; ++rr) {
        int row = row0 + rbase + rr;
        float2 v = acc[rr];
        v.x += bb.x; v.y += bb.y;
        float p = v.x * at.x + v.y * at.y;
        p += __shfl_down(p, 32);
        p += __shfl_down(p, 16);
        p += __shfl_down(p, 8);
        p += __shfl_down(p, 4);
        p += __shfl_down(p, 2);
        p += __shfl_down(p, 1);
        p = __shfl(p, 0);
        float alpha = 1.f / (1.f + expf(-p));
        v.x *= alpha; v.y *= alpha;
        if (row < M) {
            *(float2*)&out_h[(size_t)row * OUT_DIM + col * 2] = v;
            if (col == 0) out_alpha[row] = alpha;
        }
    }
}

extern "C" void kernel_launch(void* const* d_in, const int* in_sizes, int n_in,
                              void* d_out, int out_size, void* d_ws, size_t ws_size,
                              hipStream_t stream) {
    const float* feat  = (const float*)d_in[0];
    const float* W1    = (const float*)d_in[1];
    const float* b1    = (const float*)d_in[2];
    const float* attn1 = (const float*)d_in[3];
    const float* W2    = (const float*)d_in[4];
    const float* b2    = (const float*)d_in[5];
    const float* attn2 = (const float*)d_in[6];
    const int* src1 = (const int*)d_in[7];
    const int* dst1 = (const int*)d_in[8];
    const int* src2 = (const int*)d_in[9];
    const int* dst2 = (const int*)d_in[10];
    float* out = (float*)d_out;

    // workspace layout
    float* ws = (float*)d_ws;
    float* outdeg1 = ws;                                   // N_SRC1 (zeroed)
    float* outdeg2 = outdeg1 + N_SRC1;                     // N_SRC2 (zeroed)
    int*   cnt1    = (int*)(outdeg2 + N_SRC2);             // N_DST1 (zeroed)
    int*   cnt2    = cnt1 + N_DST1;                        // N_DST2 (zeroed)
    int*   offs1   = cnt2 + N_DST2;                        // N_DST1+1
    int*   cursor1 = offs1 + N_DST1 + 1;                   // N_DST1
    int*   offs2   = cursor1 + N_DST1;                     // N_DST2+1
    int*   cursor2 = offs2 + N_DST2 + 1;                   // N_DST2
    int*   elist1  = cursor2 + N_DST2;                     // E1
    int*   elist2  = elist1 + E1;                          // E2
    float* agg1    = (float*)(elist2 + E2);                // N_DST1*IN_DIM
    float* agg2    = agg1 + (size_t)N_DST1 * IN_DIM;       // N_DST2*HID_DIM
    float* h1      = agg2 + (size_t)N_DST2 * HID_DIM;      // N_DST1*HID_DIM

    // zero only the atomic-accumulated arrays (outdeg1, outdeg2, cnt1, cnt2 contiguous)
    const size_t zero_bytes = ((size_t)N_SRC1 + N_SRC2 + N_DST1 + N_DST2) * 4;
    hipMemsetAsync(d_ws, 0, zero_bytes, stream);

    count_kernel<<<(E1 + 255) / 256, 256, 0, stream>>>(src1, dst1, outdeg1, cnt1, E1);
    count_kernel<<<(E2 + 255) / 256, 256, 0, stream>>>(src2, dst2, outdeg2, cnt2, E2);
    rsqrt_kernel<<<(N_SRC1 + N_SRC2 + 255) / 256, 256, 0, stream>>>(outdeg1, N_SRC1 + N_SRC2);

    scan_kernel<<<1, 1024, 0, stream>>>(cnt1, offs1, cursor1, N_DST1);
    scan_kernel<<<1, 1024, 0, stream>>>(cnt2, offs2, cursor2, N_DST2);
    fill_kernel<<<(E1 + 255) / 256, 256, 0, stream>>>(src1, dst1, cursor1, elist1, E1);
    fill_kernel<<<(E2 + 255) / 256, 256, 0, stream>>>(src2, dst2, cursor2, elist2, E2);

    gather1_kernel<<<(N_DST1 + 3) / 4, 256, 0, stream>>>(feat, elist1, offs1, outdeg1, agg1, N_DST1);
    gemm1_gate<<<(N_DST1 + 63) / 64, 256, 0, stream>>>(agg1, W1, b1, attn1, h1, N_DST1);
    gather2_kernel<<<(N_DST2 + 3) / 4, 256, 0, stream>>>(h1, elist2, offs2, outdeg2, agg2, N_DST2);
    gemm2_gate<<<(N_DST2 + 31) / 32, 256, 0, stream>>>(agg2, W2, b2, attn2,
                                                       out, out + (size_t)N_DST2 * OUT_DIM, N_DST2);
}